// Round 12
// baseline (183.606 us; speedup 1.0000x reference)
//
#include <hip/hip_runtime.h>

// LSTM(units=64) over T=5, D_IN=1, then Dense(1, relu).  R12.
// = R9 champion structure (93us rocprof: MB=128 col-partition, Bf in
// regs, barriers between t) + SOFTWARE exp2.
// Block-size parabola closed: MB 64/128/256 = 95.8/93.0/109 -> 128.
// R10 (barrier-free) and R11 (MB=256) both regressed; occupancy pinned.
// Ledger: wave64 trans blocks issue ~16cyc; R9 busy = 60us trans +
// 10us regular at ~70% util. Last lever: move exp2 off the trans pipe.
//   exp2(w): n=rint(w); f=w-n in [-.5,.5]; 2^f = deg-5 Taylor
//   (coeffs ln2^k/k!, rel err <= 3.4e-6); scale by bitcast((n+127)<<23).
//   ~26 issue-cyc/pair (packed FMA) vs 32 for 2x v_exp_f32.
// 5 exp2 -> software; 2 rcp stay hardware. Gate algebra unchanged:
//   p=(1+ei)(1+eg), q=(1+ef):  c' = (c*p + q*(1-eg)) * rcp(p*q)
//   h = o*tanh(c') = (1-ec) * rcp((1+eo)(1+ec)),  ec = exp2(-2L*c')
// absmax expected ~1.95e-3 (Taylor err 3.4e-6 rel, below f16 rounding).
// Spill sentinel: WRITE_SIZE > 2MB. Neutral result => trans pipe was
// separate/overlapped, revert R9 and declare roofline.

typedef _Float16 f16x8 __attribute__((ext_vector_type(8)));
typedef float f32x4 __attribute__((ext_vector_type(4)));
typedef float f32x2 __attribute__((ext_vector_type(2)));

#define MB 128       // rows per block (2 groups of 64)
#define NTHREADS 256
#define HSTR 68

__device__ __forceinline__ float rcp(float x) { return __builtin_amdgcn_rcpf(x); }
__device__ __forceinline__ f32x2 fma2(f32x2 a, f32x2 b, f32x2 c) {
    return __builtin_elementwise_fma(a, b, c);
}

// software exp2 on a pair: v_rndne + pk_sub + v_cvt_i32 + 5x pk_fma +
// v_lshl_add + pk_mul.  Valid for |w| < ~120 (here |w| <= ~40).
__device__ __forceinline__ f32x2 exp2p(f32x2 w) {
    const float nx = __builtin_rintf(w.x);
    const float ny = __builtin_rintf(w.y);
    const f32x2 f = w - (f32x2){nx, ny};
    const int ix = (int)nx;
    const int iy = (int)ny;
    f32x2 p = {0.0013333558f, 0.0013333558f};            // ln2^5/120
    p = fma2(f, p, (f32x2){0.0096181291f, 0.0096181291f}); // ln2^4/24
    p = fma2(f, p, (f32x2){0.0555041087f, 0.0555041087f}); // ln2^3/6
    p = fma2(f, p, (f32x2){0.2402265069f, 0.2402265069f}); // ln2^2/2
    p = fma2(f, p, (f32x2){0.6931471806f, 0.6931471806f}); // ln2
    p = fma2(f, p, (f32x2){1.0f, 1.0f});
    f32x2 s;
    s.x = __builtin_bit_cast(float, (ix + 127) << 23);
    s.y = __builtin_bit_cast(float, (iy + 127) << 23);
    return p * s;
}

__global__ __launch_bounds__(NTHREADS, 3) void lstm_fused(
    const float* __restrict__ x,   // [B,5,1]
    const float* __restrict__ W,   // [1,256]  gate order i,f,g,o
    const float* __restrict__ U,   // [64,256]
    const float* __restrict__ b,   // [256]
    const float* __restrict__ Wd,  // [64,1]
    const float* __restrict__ bd,  // [1]
    float* __restrict__ out,       // [B,1]
    int B)
{
    __shared__ _Float16 hbuf[2][2][64 * HSTR];  // [group][parity] 34.0 KB
    __shared__ float xs[5][MB];                 // 2.5 KB, [t][row]
    __shared__ float red[2][MB];                // 1 KB
    __shared__ float wds[64];                   // 0.25 KB

    const int tid  = threadIdx.x;
    const int wv   = tid >> 6;
    const int lane = tid & 63;
    const int l15  = lane & 15;
    const int quad = lane >> 4;
    const int row0 = blockIdx.x * MB;

    // stage x transposed to [t][row]; stage Wd
    for (int i = tid; i < MB * 5; i += NTHREADS)
        xs[i % 5][i / 5] = x[row0 * 5 + i];
    if (tid < 64) wds[tid] = Wd[tid];

    const float LOG2E = 1.44269504f;
    const float gscale[4] = {-LOG2E, -LOG2E, -2.0f * LOG2E, -LOG2E};
    const float CSC = -2.0f * LOG2E;

    // U B-fragments loaded ONCE (n = gate*64 + wv*16 + l15,
    // k = kh*32 + quad*8 + j), scaled, cvt f16, pinned vs remat.
    const int ncol = wv * 16 + l15;
    float Wf[4], bf[4];
    f16x8 Bf[4][2];
#pragma unroll
    for (int g = 0; g < 4; ++g) {
        const int n = g * 64 + ncol;
        const float s = gscale[g];
        Wf[g] = W[n] * s;
        bf[g] = b[n] * s;
#pragma unroll
        for (int kh = 0; kh < 2; ++kh) {
            f16x8 v;
#pragma unroll
            for (int j = 0; j < 8; ++j) {
                const int k = kh * 32 + quad * 8 + j;
                v[j] = (_Float16)(U[k * 256 + n] * s);
            }
            Bf[g][kh] = v;
            asm volatile("" : "+v"(Bf[g][kh]));
        }
    }

    // cell state: [group][rt][pair], pair pr covers rows quad*4+2pr+{0,1}
    f32x2 cst[2][4][2];
#pragma unroll
    for (int gr = 0; gr < 2; ++gr)
#pragma unroll
        for (int a = 0; a < 4; ++a)
#pragma unroll
            for (int pr = 0; pr < 2; ++pr) cst[gr][a][pr] = (f32x2){0.f, 0.f};

    __syncthreads();  // xs visible

    // ---- t = 0 (h=0, c=0): c = i*g, h = o*tanh(c) ----
#pragma unroll
    for (int gr = 0; gr < 2; ++gr) {
#pragma unroll
        for (int rt = 0; rt < 4; ++rt) {
            const f32x4 xv = *(const f32x4*)&xs[0][gr * 64 + rt * 16 + quad * 4];
#pragma unroll
            for (int pr = 0; pr < 2; ++pr) {
                const f32x2 xp = {xv[2 * pr], xv[2 * pr + 1]};
                const f32x2 ei = exp2p(fma2(xp, (f32x2){Wf[0], Wf[0]}, (f32x2){bf[0], bf[0]}));
                const f32x2 eg = exp2p(fma2(xp, (f32x2){Wf[2], Wf[2]}, (f32x2){bf[2], bf[2]}));
                const f32x2 eo = exp2p(fma2(xp, (f32x2){Wf[3], Wf[3]}, (f32x2){bf[3], bf[3]}));
                const f32x2 pq = (1.0f + ei) * (1.0f + eg);
                const f32x2 r1 = {rcp(pq.x), rcp(pq.y)};
                const f32x2 cn = (1.0f - eg) * r1;            // i*g
                cst[gr][rt][pr] = cn;
                const f32x2 ec = exp2p(cn * CSC);
                const f32x2 dn = (1.0f + eo) * (1.0f + ec);
                const f32x2 r2 = {rcp(dn.x), rcp(dn.y)};
                const f32x2 h2 = (1.0f - ec) * r2;
                const int rb = rt * 16 + quad * 4 + 2 * pr;
                hbuf[gr][0][rb * HSTR + ncol]       = (_Float16)h2.x;
                hbuf[gr][0][(rb + 1) * HSTR + ncol] = (_Float16)h2.y;
            }
        }
    }

    // ---- t = 1..4 ----
#pragma unroll
    for (int t = 1; t < 5; ++t) {
        const int src = (t + 1) & 1;
        const int dst = t & 1;
        __syncthreads();
#pragma unroll
        for (int gr = 0; gr < 2; ++gr) {
#pragma unroll
            for (int rt = 0; rt < 4; ++rt) {
                const int arow = rt * 16 + l15;   // A layout: m = lane&15
                const f16x8 a0 = *(const f16x8*)&hbuf[gr][src][arow * HSTR + quad * 8];
                const f16x8 a1 = *(const f16x8*)&hbuf[gr][src][arow * HSTR + 32 + quad * 8];
                const f32x4 xv = *(const f32x4*)&xs[t][gr * 64 + rt * 16 + quad * 4];
                const f32x2 xlo = {xv[0], xv[1]};
                const f32x2 xhi = {xv[2], xv[3]};
                f32x4 acc[4];
#pragma unroll
                for (int g = 0; g < 4; ++g) {
                    const f32x2 wg = {Wf[g], Wf[g]};
                    const f32x2 bg = {bf[g], bf[g]};
                    const f32x2 zlo = fma2(xlo, wg, bg);
                    const f32x2 zhi = fma2(xhi, wg, bg);
                    f32x4 z = {zlo.x, zlo.y, zhi.x, zhi.y};
                    z = __builtin_amdgcn_mfma_f32_16x16x32_f16(a0, Bf[g][0], z, 0, 0, 0);
                    z = __builtin_amdgcn_mfma_f32_16x16x32_f16(a1, Bf[g][1], z, 0, 0, 0);
                    acc[g] = z;
                }
#pragma unroll
                for (int pr = 0; pr < 2; ++pr) {
                    const f32x2 ei = exp2p((f32x2){acc[0][2 * pr], acc[0][2 * pr + 1]});
                    const f32x2 ef = exp2p((f32x2){acc[1][2 * pr], acc[1][2 * pr + 1]});
                    const f32x2 eg = exp2p((f32x2){acc[2][2 * pr], acc[2][2 * pr + 1]});
                    const f32x2 eo = exp2p((f32x2){acc[3][2 * pr], acc[3][2 * pr + 1]});
                    const f32x2 p  = (1.0f + ei) * (1.0f + eg);
                    const f32x2 q  = 1.0f + ef;
                    const f32x2 num = fma2(cst[gr][rt][pr], p, q * (1.0f - eg));
                    const f32x2 pq  = p * q;
                    const f32x2 ipq = {rcp(pq.x), rcp(pq.y)};
                    const f32x2 cn  = num * ipq;
                    cst[gr][rt][pr] = cn;
                    const f32x2 ec = exp2p(cn * CSC);
                    const f32x2 dn = (1.0f + eo) * (1.0f + ec);
                    const f32x2 r2 = {rcp(dn.x), rcp(dn.y)};
                    const f32x2 h2 = (1.0f - ec) * r2;
                    const int rb = rt * 16 + quad * 4 + 2 * pr;
                    hbuf[gr][dst][rb * HSTR + ncol]       = (_Float16)h2.x;
                    hbuf[gr][dst][(rb + 1) * HSTR + ncol] = (_Float16)h2.y;
                }
            }
        }
    }

    __syncthreads();  // h(t=4) complete in hbuf[*][0]

    // Dense(1, relu): each thread sums 32 of the 64 units for one row.
    {
        const int row = tid & 127;          // 0..127
        const int qh  = tid >> 7;           // 0..1
        const int gr  = row >> 6;
        const int rl  = row & 63;
        float s = 0.0f;
#pragma unroll
        for (int j = 0; j < 32; ++j)
            s += (float)hbuf[gr][0][rl * HSTR + qh * 32 + j] * wds[qh * 32 + j];
        red[qh][row] = s;
    }
    __syncthreads();
    if (tid < MB) {
        const float r = red[0][tid] + red[1][tid] + bd[0];
        out[row0 + tid] = fmaxf(r, 0.0f);
    }
}

extern "C" void kernel_launch(void* const* d_in, const int* in_sizes, int n_in,
                              void* d_out, int out_size, void* d_ws, size_t ws_size,
                              hipStream_t stream) {
    const float* x  = (const float*)d_in[0];
    const float* W  = (const float*)d_in[1];
    const float* U  = (const float*)d_in[2];
    const float* b  = (const float*)d_in[3];
    const float* Wd = (const float*)d_in[4];
    const float* bd = (const float*)d_in[5];
    float* out = (float*)d_out;
    const int B = in_sizes[0] / 5;
    const int grid = B / MB;   // 2048 blocks
    lstm_fused<<<grid, NTHREADS, 0, stream>>>(x, W, U, b, Wd, bd, out, B);
}

// Round 13
// 139.167 us; speedup vs baseline: 1.3193x; 1.3193x over previous
//
#include <hip/hip_runtime.h>

// LSTM(units=64) over T=5, D_IN=1, then Dense(1, relu).  R13 = R9 revert.
// CHAMPION structure (93.0us rocprof best): MB=128 column partition,
// wave w owns gate-cols [w*16,w*16+16) of all 4 gates, U B-fragments
// register-resident (asm-pinned vs remat), barriers between timesteps,
// gates in packed-fp32 (v_pk_*) exp2 + merged-rcp algebra:
//   p=(1+ei)(1+eg), q=(1+ef):  c' = (c*p + q*(1-eg)) * rcp(p*q)
//   h = o*tanh(c') = (1-ec) * rcp((1+eo)(1+ec)),  ec = exp2(-2L*c')
// (5 hw exp2 + 2 hw rcp per cell -- minimal; see survey below)
//
// Optimization survey (R1-R12), all counters-verified:
//  - remat fix + exp2 algebra:  133 -> 102us   (R2-R4)
//  - packed fp32 cell-pairs:    102 -> 95.8us  (R8)
//  - block fatness parabola: MB 64/128/256 = 95.8/93.0/109 (R9/R11)
//  - occupancy: PINNED ~3 waves/SIMD by unified VGPR+AGPR file;
//    launch_bounds caps either no-op (R7) or spill (R6)
//  - barrier-free row partition: regressed 104us (R10) -- MFMA operands
//    must stay in registers
//  - software exp2 (deg-5 Taylor): regressed 147us (R12) -- hw trans
//    is ~2x cheaper in issue terms than packed-FMA emulation
//  - poly/rational tanh: needs degree>=13 on [-5,5] (pole i*pi/2),
//    costs >= the exp2 it replaces (paper analysis)
// Structural ceiling: 5.9e8 hw transcendentals ~ 58-60us trans-pipe
// occupancy; 93us wall = ~65% fill, residual = exp2->rcp->exp2 dep
// chains at the hw-pinned residency. This is the practical roofline.
// absmax: exactly 1.953125e-3 (f16 h round-trip quantization).

typedef _Float16 f16x8 __attribute__((ext_vector_type(8)));
typedef float f32x4 __attribute__((ext_vector_type(4)));
typedef float f32x2 __attribute__((ext_vector_type(2)));

#define MB 128       // rows per block (2 groups of 64)
#define NTHREADS 256
#define HSTR 68

__device__ __forceinline__ float ex2(float x) { return __builtin_amdgcn_exp2f(x); }
__device__ __forceinline__ float rcp(float x) { return __builtin_amdgcn_rcpf(x); }
__device__ __forceinline__ f32x2 fma2(f32x2 a, f32x2 b, f32x2 c) {
    return __builtin_elementwise_fma(a, b, c);
}

__global__ __launch_bounds__(NTHREADS, 3) void lstm_fused(
    const float* __restrict__ x,   // [B,5,1]
    const float* __restrict__ W,   // [1,256]  gate order i,f,g,o
    const float* __restrict__ U,   // [64,256]
    const float* __restrict__ b,   // [256]
    const float* __restrict__ Wd,  // [64,1]
    const float* __restrict__ bd,  // [1]
    float* __restrict__ out,       // [B,1]
    int B)
{
    __shared__ _Float16 hbuf[2][2][64 * HSTR];  // [group][parity] 34.0 KB
    __shared__ float xs[5][MB];                 // 2.5 KB, [t][row]
    __shared__ float red[2][MB];                // 1 KB
    __shared__ float wds[64];                   // 0.25 KB

    const int tid  = threadIdx.x;
    const int wv   = tid >> 6;
    const int lane = tid & 63;
    const int l15  = lane & 15;
    const int quad = lane >> 4;
    const int row0 = blockIdx.x * MB;

    // stage x transposed to [t][row]; stage Wd
    for (int i = tid; i < MB * 5; i += NTHREADS)
        xs[i % 5][i / 5] = x[row0 * 5 + i];
    if (tid < 64) wds[tid] = Wd[tid];

    const float LOG2E = 1.44269504f;
    const float gscale[4] = {-LOG2E, -LOG2E, -2.0f * LOG2E, -LOG2E};
    const float CSC = -2.0f * LOG2E;

    // U B-fragments loaded ONCE (n = gate*64 + wv*16 + l15,
    // k = kh*32 + quad*8 + j), scaled, cvt f16, pinned vs remat.
    const int ncol = wv * 16 + l15;
    float Wf[4], bf[4];
    f16x8 Bf[4][2];
#pragma unroll
    for (int g = 0; g < 4; ++g) {
        const int n = g * 64 + ncol;
        const float s = gscale[g];
        Wf[g] = W[n] * s;
        bf[g] = b[n] * s;
#pragma unroll
        for (int kh = 0; kh < 2; ++kh) {
            f16x8 v;
#pragma unroll
            for (int j = 0; j < 8; ++j) {
                const int k = kh * 32 + quad * 8 + j;
                v[j] = (_Float16)(U[k * 256 + n] * s);
            }
            Bf[g][kh] = v;
            asm volatile("" : "+v"(Bf[g][kh]));
        }
    }

    // cell state: [group][rt][pair], pair pr covers rows quad*4+2pr+{0,1}
    f32x2 cst[2][4][2];
#pragma unroll
    for (int gr = 0; gr < 2; ++gr)
#pragma unroll
        for (int a = 0; a < 4; ++a)
#pragma unroll
            for (int pr = 0; pr < 2; ++pr) cst[gr][a][pr] = (f32x2){0.f, 0.f};

    __syncthreads();  // xs visible

    // ---- t = 0 (h=0, c=0): c = i*g, h = o*tanh(c) ----
#pragma unroll
    for (int gr = 0; gr < 2; ++gr) {
#pragma unroll
        for (int rt = 0; rt < 4; ++rt) {
            const f32x4 xv = *(const f32x4*)&xs[0][gr * 64 + rt * 16 + quad * 4];
#pragma unroll
            for (int pr = 0; pr < 2; ++pr) {
                const f32x2 xp = {xv[2 * pr], xv[2 * pr + 1]};
                const f32x2 zi = fma2(xp, (f32x2){Wf[0], Wf[0]}, (f32x2){bf[0], bf[0]});
                const f32x2 zg = fma2(xp, (f32x2){Wf[2], Wf[2]}, (f32x2){bf[2], bf[2]});
                const f32x2 zo = fma2(xp, (f32x2){Wf[3], Wf[3]}, (f32x2){bf[3], bf[3]});
                const f32x2 ei = {ex2(zi.x), ex2(zi.y)};
                const f32x2 eg = {ex2(zg.x), ex2(zg.y)};
                const f32x2 eo = {ex2(zo.x), ex2(zo.y)};
                const f32x2 pq = (1.0f + ei) * (1.0f + eg);
                const f32x2 r1 = {rcp(pq.x), rcp(pq.y)};
                const f32x2 cn = (1.0f - eg) * r1;            // i*g
                cst[gr][rt][pr] = cn;
                const f32x2 sc = cn * CSC;
                const f32x2 ec = {ex2(sc.x), ex2(sc.y)};
                const f32x2 dn = (1.0f + eo) * (1.0f + ec);
                const f32x2 r2 = {rcp(dn.x), rcp(dn.y)};
                const f32x2 h2 = (1.0f - ec) * r2;
                const int rb = rt * 16 + quad * 4 + 2 * pr;
                hbuf[gr][0][rb * HSTR + ncol]       = (_Float16)h2.x;
                hbuf[gr][0][(rb + 1) * HSTR + ncol] = (_Float16)h2.y;
            }
        }
    }

    // ---- t = 1..4 ----
#pragma unroll
    for (int t = 1; t < 5; ++t) {
        const int src = (t + 1) & 1;
        const int dst = t & 1;
        __syncthreads();
#pragma unroll
        for (int gr = 0; gr < 2; ++gr) {
#pragma unroll
            for (int rt = 0; rt < 4; ++rt) {
                const int arow = rt * 16 + l15;   // A layout: m = lane&15
                const f16x8 a0 = *(const f16x8*)&hbuf[gr][src][arow * HSTR + quad * 8];
                const f16x8 a1 = *(const f16x8*)&hbuf[gr][src][arow * HSTR + 32 + quad * 8];
                const f32x4 xv = *(const f32x4*)&xs[t][gr * 64 + rt * 16 + quad * 4];
                const f32x2 xlo = {xv[0], xv[1]};
                const f32x2 xhi = {xv[2], xv[3]};
                f32x4 acc[4];
#pragma unroll
                for (int g = 0; g < 4; ++g) {
                    const f32x2 wg = {Wf[g], Wf[g]};
                    const f32x2 bg = {bf[g], bf[g]};
                    const f32x2 zlo = fma2(xlo, wg, bg);
                    const f32x2 zhi = fma2(xhi, wg, bg);
                    f32x4 z = {zlo.x, zlo.y, zhi.x, zhi.y};
                    z = __builtin_amdgcn_mfma_f32_16x16x32_f16(a0, Bf[g][0], z, 0, 0, 0);
                    z = __builtin_amdgcn_mfma_f32_16x16x32_f16(a1, Bf[g][1], z, 0, 0, 0);
                    acc[g] = z;
                }
#pragma unroll
                for (int pr = 0; pr < 2; ++pr) {
                    const f32x2 ei = {ex2(acc[0][2 * pr]), ex2(acc[0][2 * pr + 1])};
                    const f32x2 ef = {ex2(acc[1][2 * pr]), ex2(acc[1][2 * pr + 1])};
                    const f32x2 eg = {ex2(acc[2][2 * pr]), ex2(acc[2][2 * pr + 1])};
                    const f32x2 eo = {ex2(acc[3][2 * pr]), ex2(acc[3][2 * pr + 1])};
                    const f32x2 p  = (1.0f + ei) * (1.0f + eg);
                    const f32x2 q  = 1.0f + ef;
                    const f32x2 num = fma2(cst[gr][rt][pr], p, q * (1.0f - eg));
                    const f32x2 pq  = p * q;
                    const f32x2 ipq = {rcp(pq.x), rcp(pq.y)};
                    const f32x2 cn  = num * ipq;
                    cst[gr][rt][pr] = cn;
                    const f32x2 sc = cn * CSC;
                    const f32x2 ec = {ex2(sc.x), ex2(sc.y)};
                    const f32x2 dn = (1.0f + eo) * (1.0f + ec);
                    const f32x2 r2 = {rcp(dn.x), rcp(dn.y)};
                    const f32x2 h2 = (1.0f - ec) * r2;
                    const int rb = rt * 16 + quad * 4 + 2 * pr;
                    hbuf[gr][dst][rb * HSTR + ncol]       = (_Float16)h2.x;
                    hbuf[gr][dst][(rb + 1) * HSTR + ncol] = (_Float16)h2.y;
                }
            }
        }
    }

    __syncthreads();  // h(t=4) complete in hbuf[*][0]

    // Dense(1, relu): each thread sums 32 of the 64 units for one row.
    {
        const int row = tid & 127;          // 0..127
        const int qh  = tid >> 7;           // 0..1
        const int gr  = row >> 6;
        const int rl  = row & 63;
        float s = 0.0f;
#pragma unroll
        for (int j = 0; j < 32; ++j)
            s += (float)hbuf[gr][0][rl * HSTR + qh * 32 + j] * wds[qh * 32 + j];
        red[qh][row] = s;
    }
    __syncthreads();
    if (tid < MB) {
        const float r = red[0][tid] + red[1][tid] + bd[0];
        out[row0 + tid] = fmaxf(r, 0.0f);
    }
}

extern "C" void kernel_launch(void* const* d_in, const int* in_sizes, int n_in,
                              void* d_out, int out_size, void* d_ws, size_t ws_size,
                              hipStream_t stream) {
    const float* x  = (const float*)d_in[0];
    const float* W  = (const float*)d_in[1];
    const float* U  = (const float*)d_in[2];
    const float* b  = (const float*)d_in[3];
    const float* Wd = (const float*)d_in[4];
    const float* bd = (const float*)d_in[5];
    float* out = (float*)d_out;
    const int B = in_sizes[0] / 5;
    const int grid = B / MB;   // 2048 blocks
    lstm_fused<<<grid, NTHREADS, 0, stream>>>(x, W, U, b, Wd, bd, out, B);
}